// Round 10
// baseline (122.473 us; speedup 1.0000x reference)
//
#include <hip/hip_runtime.h>
#include <hip/hip_bf16.h>

// Problem constants
constexpr int BATCH = 4096;
constexpr int IN    = 512;
constexpr int OUT   = 512;
constexpr int ORD   = 8;
constexpr int NK    = ORD + 1;        // 9
constexpr float FA  = 1.0f, FB = 1.0f;

// GEMM inner dim EXCLUDES k=0 (J0 == 1 -> bias term), KP = 4096
constexpr int KP     = IN * ORD;
constexpr int SPLITK = 4;                      // 512 blocks -> 2 blocks/CU
constexpr int KT     = KP / (32 * SPLITK);     // 32 K-steps (of 32) per block
constexpr int KS_TOT = KP / 32;                // 128 k-steps total

// Fragment-major layouts (written by prep, read by gemm):
//   A2[mt][ks] = 64 lanes x 16B, element (b = mt*16 + (lane&15),
//                K = ks*32 + (lane>>4)*8 + j)  -- exactly the MFMA A-operand.
//   B2[nt][ks] likewise with o rows. One wave frag load = lane*16B, coalesced.

typedef __attribute__((ext_vector_type(8))) short short8;   // 8 bf16
typedef __attribute__((ext_vector_type(4))) float floatx4;  // MFMA C/D

__device__ __forceinline__ short f32_to_bf16bits(float f) {
    __hip_bfloat16 h = __float2bfloat16(f);
    return *(short*)&h;
}

// ---------------------------------------------------------------------------
// Kernel 1 (fused prep):
//  blocks [0,1024):      Jacobi -> A2 fragment-major
//  blocks [1024,1152):   coeff*w -> B2 fragment-major
//  blocks [1152,1280):   bias[o] = sum_i coeff[o,i,0]*w[o,i] (1 wave per o)
// ---------------------------------------------------------------------------
__global__ __launch_bounds__(256) void prep(const float* __restrict__ x,
                                            const float* __restrict__ w,
                                            const float* __restrict__ coeff,
                                            short* __restrict__ A2,
                                            short* __restrict__ B2,
                                            float* __restrict__ bias) {
    const int bid  = blockIdx.x;
    const int tid  = threadIdx.x;
    const int lane = tid & 63;
    const int quad = lane >> 4;
    const int l15  = lane & 15;

    if (bid < 1024) {
        // ---- Jacobi branch: mt = bid/4, thread: b = mt*16+l15, 8 i's ----
        const int mt  = bid >> 2;
        const int sub = ((bid & 3) << 2) + (tid >> 6);   // 0..15
        const int b   = mt * 16 + l15;
        const int i0  = sub * 32 + quad * 8;
        const float* xr = x + (size_t)b * IN + i0;
        float t[8];
#pragma unroll
        for (int e = 0; e < 8; ++e) {
            float xc = fminf(fmaxf(xr[e], -9.0f), 9.0f);
            float ex = __expf(2.0f * xc);
            t[e] = (ex - 1.0f) / (ex + 1.0f);
        }
        float pp[8], pc[8];
#pragma unroll
        for (int e = 0; e < 8; ++e) {
            pp[e] = 1.0f;
            pc[e] = 0.5f * (FA + FB + 2.0f) * t[e] - 0.5f * (FA - FB);
        }
        {
            short8 v;
#pragma unroll
            for (int e = 0; e < 8; ++e) v[e] = f32_to_bf16bits(pc[e]);
            *(short8*)(A2 + (((size_t)mt * KS_TOT + sub) * 64 + lane) * 8) = v;
        }
#pragma unroll
        for (int n = 2; n <= ORD; ++n) {
            float fn = (float)n;
            float k1 = (2.f*fn+FA+FB)*(2.f*fn+FA+FB-1.f) / (2.f*fn*(fn+FA+FB));
            float k2 = (2.f*fn+FA+FB-1.f)*(FA*FA-FB*FB) /
                       (2.f*fn*(fn+FA+FB)*(2.f*fn+FA+FB-2.f));
            float k3 = (fn+FA-1.f)*(fn+FB-1.f)*(2.f*fn+FA+FB) /
                       (fn*(fn+FA+FB)*(2.f*fn+FA+FB-2.f));
            short8 v;
#pragma unroll
            for (int e = 0; e < 8; ++e) {
                float nx = (k1*t[e] + k2)*pc[e] - k3*pp[e];
                pp[e] = pc[e]; pc[e] = nx;
                v[e] = f32_to_bf16bits(nx);
            }
            const int ks = (n - 1) * 16 + sub;
            *(short8*)(A2 + (((size_t)mt * KS_TOT + ks) * 64 + lane) * 8) = v;
        }
    } else if (bid < 1152) {
        // ---- coeff*w branch: nt = (bid-1024)/4, o = nt*16+l15, 8 i's ----
        const int b2  = bid - 1024;
        const int nt  = b2 >> 2;
        const int sub = ((b2 & 3) << 2) + (tid >> 6);
        const int o   = nt * 16 + l15;
        const int i0  = sub * 32 + quad * 8;
        const float* wr = w + (size_t)o * IN + i0;
        float wv[8];
#pragma unroll
        for (int e = 0; e < 8; ++e) wv[e] = wr[e];
        const float* cf = coeff + ((size_t)o * IN + i0) * NK;  // [e][k] stride 9
#pragma unroll
        for (int n = 1; n <= ORD; ++n) {
            short8 v;
#pragma unroll
            for (int e = 0; e < 8; ++e)
                v[e] = f32_to_bf16bits(cf[(size_t)e * NK + n] * wv[e]);
            const int ks = (n - 1) * 16 + sub;
            *(short8*)(B2 + (((size_t)nt * KS_TOT + ks) * 64 + lane) * 8) = v;
        }
    } else {
        // ---- bias branch: 128 blocks, one wave per output o ----
        const int bb = bid - 1152;                       // 0..127
        const int o  = bb * 4 + (tid >> 6);
        const float* cf = coeff + (size_t)o * IN * NK;
        const float* wr = w + (size_t)o * IN;
        float acc = 0.0f;
#pragma unroll
        for (int r = 0; r < IN / 64; ++r) {
            int i = r * 64 + lane;
            acc = fmaf(cf[(size_t)i * NK], wr[i], acc);
        }
#pragma unroll
        for (int off = 32; off >= 1; off >>= 1)
            acc += __shfl_xor(acc, off, 64);
        if (lane == 0) bias[o] = acc;
    }
}

// ---------------------------------------------------------------------------
// Kernel 2: split-K GEMM, NO LDS / NO BARRIERS / NO REDUCE KERNEL.
// Fragment loads directly from fragment-major A2/B2 (coalesced dwordx4).
// Epilogue: fp32 atomicAdd partials straight into out (commutative -> no
// fences/counters needed, unlike r7's fixup). z==0 blocks fold in bias.
// out zeroed by an on-stream memset before launch.
// ---------------------------------------------------------------------------
__global__ __launch_bounds__(256) void gemm_splitk(
        const short* __restrict__ A2,   // [256][128] x 1KB lines
        const short* __restrict__ B2,   // [32][128]  x 1KB lines
        const float* __restrict__ bias, // [512]
        float* __restrict__ out)        // [4096][512] fp32, pre-zeroed
{
    const int tid  = threadIdx.x;
    const int lane = tid & 63;
    const int quad = lane >> 4;
    const int l15  = lane & 15;
    const int mw   = (tid >> 6) & 1;
    const int nw   = tid >> 7;
    const int bx = blockIdx.x;          // 0..31  (m-tiles of 128)
    const int by = blockIdx.y;          // 0..3   (n-tiles of 128)
    const int z  = blockIdx.z;          // 0..3

    const short* pa[4];
    const short* pb[4];
#pragma unroll
    for (int i = 0; i < 4; ++i)
        pa[i] = A2 + (((size_t)(bx * 8 + mw * 4 + i) * KS_TOT + z * KT) * 64 + lane) * 8;
#pragma unroll
    for (int j = 0; j < 4; ++j)
        pb[j] = B2 + (((size_t)(by * 8 + nw * 4 + j) * KS_TOT + z * KT) * 64 + lane) * 8;

    floatx4 acc[4][4];
#pragma unroll
    for (int i = 0; i < 4; ++i)
#pragma unroll
        for (int j = 0; j < 4; ++j) acc[i][j] = (floatx4)0.0f;

#pragma unroll 4
    for (int kt = 0; kt < KT; ++kt) {
        short8 af[4], bfr[4];
#pragma unroll
        for (int i = 0; i < 4; ++i) { af[i]  = *(const short8*)pa[i]; pa[i] += 512; }
#pragma unroll
        for (int j = 0; j < 4; ++j) { bfr[j] = *(const short8*)pb[j]; pb[j] += 512; }
#pragma unroll
        for (int i = 0; i < 4; ++i)
#pragma unroll
            for (int j = 0; j < 4; ++j)
                acc[i][j] = __builtin_amdgcn_mfma_f32_16x16x32_bf16(
                                af[i], bfr[j], acc[i][j], 0, 0, 0);
    }

    // epilogue: C/D layout col = lane&15, row = quad*4 + reg
    const int m0 = bx * 128, n0 = by * 128;
    float bv[4];
#pragma unroll
    for (int j = 0; j < 4; ++j)
        bv[j] = (z == 0) ? bias[n0 + nw * 64 + j * 16 + l15] : 0.0f;
#pragma unroll
    for (int i = 0; i < 4; ++i) {
        const int r0 = m0 + mw * 64 + i * 16 + quad * 4;
#pragma unroll
        for (int j = 0; j < 4; ++j) {
            const int c = n0 + nw * 64 + j * 16 + l15;
#pragma unroll
            for (int r = 0; r < 4; ++r)
                unsafeAtomicAdd(&out[(size_t)(r0 + r) * OUT + c],
                                acc[i][j][r] + bv[j]);
        }
    }
}

// ---------------------------------------------------------------------------
extern "C" void kernel_launch(void* const* d_in, const int* in_sizes, int n_in,
                              void* d_out, int out_size, void* d_ws, size_t ws_size,
                              hipStream_t stream) {
    const float* x     = (const float*)d_in[0];   // [4096,512]
    const float* w     = (const float*)d_in[1];   // [512,512]
    const float* coeff = (const float*)d_in[2];   // [512,512,9]
    float* out = (float*)d_out;                   // [4096,512]

    // workspace layout (bytes)
    char* ws = (char*)d_ws;
    short* A2 = (short*)ws;                                            // 33,554,432 B
    char* p1c = ws + (size_t)BATCH * KP * 2;
    short* B2 = (short*)p1c;                                           //  4,194,304 B
    float* bias = (float*)(p1c + (size_t)OUT * KP * 2);                //      2,048 B

    hipMemsetAsync(out, 0, (size_t)BATCH * OUT * sizeof(float), stream);
    prep<<<1280, 256, 0, stream>>>(x, w, coeff, A2, B2, bias);
    gemm_splitk<<<dim3(32, 4, SPLITK), 256, 0, stream>>>(A2, B2, bias, out);
}

// Round 11
// 102.618 us; speedup vs baseline: 1.1935x; 1.1935x over previous
//
#include <hip/hip_runtime.h>
#include <hip/hip_bf16.h>

// Problem constants
constexpr int BATCH = 4096;
constexpr int IN    = 512;
constexpr int OUT   = 512;
constexpr int ORD   = 8;
constexpr int NK    = ORD + 1;        // 9
constexpr float FA  = 1.0f, FB = 1.0f;

// GEMM inner dim EXCLUDES k=0 (J0 == 1 -> bias term), KP = 4096
constexpr int KP     = IN * ORD;
constexpr int SPLITK = 4;                      // 512 blocks -> 2 blocks/CU
constexpr int KT     = KP / (32 * SPLITK);     // 32 K-steps (of 32) per block
constexpr int KS_TOT = KP / 32;                // 128 k-steps total

// Fragment-major layouts (written by prep, read by gemm):
//   A2[mt][ks] = 64 lanes x 16B, element (b = mt*16 + (lane&15),
//                K = ks*32 + (lane>>4)*8 + j)  -- exactly the MFMA A-operand.
//   B2[nt][ks] likewise with o rows. One wave frag load = lane*16B, coalesced.

typedef __attribute__((ext_vector_type(8))) short short8;   // 8 bf16
typedef __attribute__((ext_vector_type(4))) float floatx4;  // MFMA C/D

__device__ __forceinline__ float bf16bits_to_f32(short s) {
    union { unsigned int u; float f; } cv;
    cv.u = ((unsigned int)(unsigned short)s) << 16;
    return cv.f;
}
__device__ __forceinline__ short f32_to_bf16bits(float f) {
    __hip_bfloat16 h = __float2bfloat16(f);
    return *(short*)&h;
}

// ---------------------------------------------------------------------------
// Kernel 1 (fused prep):
//  blocks [0,1024):      Jacobi -> A2 fragment-major
//  blocks [1024,1152):   coeff*w -> B2 fragment-major
//  blocks [1152,1280):   bias[o] = sum_i coeff[o,i,0]*w[o,i] (1 wave per o)
// ---------------------------------------------------------------------------
__global__ __launch_bounds__(256) void prep(const float* __restrict__ x,
                                            const float* __restrict__ w,
                                            const float* __restrict__ coeff,
                                            short* __restrict__ A2,
                                            short* __restrict__ B2,
                                            float* __restrict__ bias) {
    const int bid  = blockIdx.x;
    const int tid  = threadIdx.x;
    const int lane = tid & 63;
    const int quad = lane >> 4;
    const int l15  = lane & 15;

    if (bid < 1024) {
        // ---- Jacobi branch: mt = bid/4, thread: b = mt*16+l15, 8 i's ----
        const int mt  = bid >> 2;
        const int sub = ((bid & 3) << 2) + (tid >> 6);   // 0..15
        const int b   = mt * 16 + l15;
        const int i0  = sub * 32 + quad * 8;
        const float* xr = x + (size_t)b * IN + i0;
        float t[8];
#pragma unroll
        for (int e = 0; e < 8; ++e) {
            float xc = fminf(fmaxf(xr[e], -9.0f), 9.0f);
            float ex = __expf(2.0f * xc);
            t[e] = (ex - 1.0f) / (ex + 1.0f);
        }
        float pp[8], pc[8];
#pragma unroll
        for (int e = 0; e < 8; ++e) {
            pp[e] = 1.0f;
            pc[e] = 0.5f * (FA + FB + 2.0f) * t[e] - 0.5f * (FA - FB);
        }
        {
            short8 v;
#pragma unroll
            for (int e = 0; e < 8; ++e) v[e] = f32_to_bf16bits(pc[e]);
            *(short8*)(A2 + (((size_t)mt * KS_TOT + sub) * 64 + lane) * 8) = v;
        }
#pragma unroll
        for (int n = 2; n <= ORD; ++n) {
            float fn = (float)n;
            float k1 = (2.f*fn+FA+FB)*(2.f*fn+FA+FB-1.f) / (2.f*fn*(fn+FA+FB));
            float k2 = (2.f*fn+FA+FB-1.f)*(FA*FA-FB*FB) /
                       (2.f*fn*(fn+FA+FB)*(2.f*fn+FA+FB-2.f));
            float k3 = (fn+FA-1.f)*(fn+FB-1.f)*(2.f*fn+FA+FB) /
                       (fn*(fn+FA+FB)*(2.f*fn+FA+FB-2.f));
            short8 v;
#pragma unroll
            for (int e = 0; e < 8; ++e) {
                float nx = (k1*t[e] + k2)*pc[e] - k3*pp[e];
                pp[e] = pc[e]; pc[e] = nx;
                v[e] = f32_to_bf16bits(nx);
            }
            const int ks = (n - 1) * 16 + sub;
            *(short8*)(A2 + (((size_t)mt * KS_TOT + ks) * 64 + lane) * 8) = v;
        }
    } else if (bid < 1152) {
        // ---- coeff*w branch: nt = (bid-1024)/4, o = nt*16+l15, 8 i's ----
        const int b2  = bid - 1024;
        const int nt  = b2 >> 2;
        const int sub = ((b2 & 3) << 2) + (tid >> 6);
        const int o   = nt * 16 + l15;
        const int i0  = sub * 32 + quad * 8;
        const float* wr = w + (size_t)o * IN + i0;
        float wv[8];
#pragma unroll
        for (int e = 0; e < 8; ++e) wv[e] = wr[e];
        const float* cf = coeff + ((size_t)o * IN + i0) * NK;  // [e][k] stride 9
#pragma unroll
        for (int n = 1; n <= ORD; ++n) {
            short8 v;
#pragma unroll
            for (int e = 0; e < 8; ++e)
                v[e] = f32_to_bf16bits(cf[(size_t)e * NK + n] * wv[e]);
            const int ks = (n - 1) * 16 + sub;
            *(short8*)(B2 + (((size_t)nt * KS_TOT + ks) * 64 + lane) * 8) = v;
        }
    } else {
        // ---- bias branch: 128 blocks, one wave per output o ----
        const int bb = bid - 1152;                       // 0..127
        const int o  = bb * 4 + (tid >> 6);
        const float* cf = coeff + (size_t)o * IN * NK;
        const float* wr = w + (size_t)o * IN;
        float acc = 0.0f;
#pragma unroll
        for (int r = 0; r < IN / 64; ++r) {
            int i = r * 64 + lane;
            acc = fmaf(cf[(size_t)i * NK], wr[i], acc);
        }
#pragma unroll
        for (int off = 32; off >= 1; off >>= 1)
            acc += __shfl_xor(acc, off, 64);
        if (lane == 0) bias[o] = acc;
    }
}

// ---------------------------------------------------------------------------
// Kernel 2: split-K GEMM, no LDS/barriers, EXPLICIT 2-SLOT REGISTER PIPELINE.
// r10 counters: VGPR=96 -> compiler allocated no prefetch regs; each K-step
// was load->vmcnt(0)->mfma with full L2/HBM latency exposed (MfmaUtil 13%).
// Here: preload k0,k1; body issues mfma(slot) then loads kt+2 into that slot
// -> each load covered by ~2 mfma phases + 7 co-resident waves.
// ---------------------------------------------------------------------------
__global__ __launch_bounds__(256, 2) void gemm_splitk(
        const short* __restrict__ A2,   // [256][128] x 1KB lines
        const short* __restrict__ B2,   // [32][128]  x 1KB lines
        __hip_bfloat16* __restrict__ P) // [SPLITK][4096][512] bf16
{
    const int tid  = threadIdx.x;
    const int lane = tid & 63;
    const int quad = lane >> 4;
    const int l15  = lane & 15;
    const int mw   = (tid >> 6) & 1;
    const int nw   = tid >> 7;
    const int bx = blockIdx.x;          // 0..31  (m-tiles of 128)
    const int by = blockIdx.y;          // 0..3   (n-tiles of 128)
    const int z  = blockIdx.z;          // 0..3

    const short* pa[4];
    const short* pb[4];
#pragma unroll
    for (int i = 0; i < 4; ++i)
        pa[i] = A2 + (((size_t)(bx * 8 + mw * 4 + i) * KS_TOT + z * KT) * 64 + lane) * 8;
#pragma unroll
    for (int j = 0; j < 4; ++j)
        pb[j] = B2 + (((size_t)(by * 8 + nw * 4 + j) * KS_TOT + z * KT) * 64 + lane) * 8;

    floatx4 acc[4][4];
#pragma unroll
    for (int i = 0; i < 4; ++i)
#pragma unroll
        for (int j = 0; j < 4; ++j) acc[i][j] = (floatx4)0.0f;

    // 2-slot pipeline registers
    short8 a0[4], b0[4], a1[4], b1[4];
#pragma unroll
    for (int i = 0; i < 4; ++i) { a0[i] = *(const short8*)(pa[i]);       b0[i] = *(const short8*)(pb[i]); }
#pragma unroll
    for (int i = 0; i < 4; ++i) { a1[i] = *(const short8*)(pa[i] + 512); b1[i] = *(const short8*)(pb[i] + 512); }

    for (int kt = 0; kt < KT; kt += 2) {
        // consume slot 0 (kt), then refill with kt+2
#pragma unroll
        for (int i = 0; i < 4; ++i)
#pragma unroll
            for (int j = 0; j < 4; ++j)
                acc[i][j] = __builtin_amdgcn_mfma_f32_16x16x32_bf16(
                                a0[i], b0[j], acc[i][j], 0, 0, 0);
        if (kt + 2 < KT) {
#pragma unroll
            for (int i = 0; i < 4; ++i) {
                a0[i] = *(const short8*)(pa[i] + (kt + 2) * 512);
                b0[i] = *(const short8*)(pb[i] + (kt + 2) * 512);
            }
        }
        // consume slot 1 (kt+1), then refill with kt+3
#pragma unroll
        for (int i = 0; i < 4; ++i)
#pragma unroll
            for (int j = 0; j < 4; ++j)
                acc[i][j] = __builtin_amdgcn_mfma_f32_16x16x32_bf16(
                                a1[i], b1[j], acc[i][j], 0, 0, 0);
        if (kt + 3 < KT) {
#pragma unroll
            for (int i = 0; i < 4; ++i) {
                a1[i] = *(const short8*)(pa[i] + (kt + 3) * 512);
                b1[i] = *(const short8*)(pb[i] + (kt + 3) * 512);
            }
        }
    }

    // epilogue: C/D layout col = lane&15, row = quad*4 + reg; bf16 partials
    __hip_bfloat16* Pz = P + (size_t)z * BATCH * OUT;
    const int m0 = bx * 128, n0 = by * 128;
#pragma unroll
    for (int i = 0; i < 4; ++i) {
        const int r0 = m0 + mw * 64 + i * 16 + quad * 4;
#pragma unroll
        for (int j = 0; j < 4; ++j) {
            const int c = n0 + nw * 64 + j * 16 + l15;
#pragma unroll
            for (int r = 0; r < 4; ++r)
                Pz[(size_t)(r0 + r) * OUT + c] = __float2bfloat16(acc[i][j][r]);
        }
    }
}

// ---------------------------------------------------------------------------
// Kernel 3: out[b,o] = sum_z P[z][b,o] + bias[o]   (8 outputs per thread)
// ---------------------------------------------------------------------------
__global__ __launch_bounds__(256) void reducek(const short* __restrict__ P,
                                               const float* __restrict__ bias,
                                               float* __restrict__ out) {
    const int j = blockIdx.x * 256 + threadIdx.x;
    const size_t base = (size_t)j * 8;
    constexpr size_t PLANE = (size_t)BATCH * OUT;

    float s[8];
    {
        short8 v = *(const short8*)(P + base);
#pragma unroll
        for (int e = 0; e < 8; ++e) s[e] = bf16bits_to_f32(v[e]);
    }
#pragma unroll
    for (int z = 1; z < SPLITK; ++z) {
        short8 v = *(const short8*)(P + z * PLANE + base);
#pragma unroll
        for (int e = 0; e < 8; ++e) s[e] += bf16bits_to_f32(v[e]);
    }
    const int o0 = (int)(base & (OUT - 1));
    const floatx4 b0 = *(const floatx4*)(bias + o0);
    const floatx4 b1 = *(const floatx4*)(bias + o0 + 4);
    floatx4 r0 = {s[0] + b0[0], s[1] + b0[1], s[2] + b0[2], s[3] + b0[3]};
    floatx4 r1 = {s[4] + b1[0], s[5] + b1[1], s[6] + b1[2], s[7] + b1[3]};
    *(floatx4*)(out + base)     = r0;
    *(floatx4*)(out + base + 4) = r1;
}

// ---------------------------------------------------------------------------
extern "C" void kernel_launch(void* const* d_in, const int* in_sizes, int n_in,
                              void* d_out, int out_size, void* d_ws, size_t ws_size,
                              hipStream_t stream) {
    const float* x     = (const float*)d_in[0];   // [4096,512]
    const float* w     = (const float*)d_in[1];   // [512,512]
    const float* coeff = (const float*)d_in[2];   // [512,512,9]
    float* out = (float*)d_out;                   // [4096,512]

    // workspace layout (bytes)
    char* ws = (char*)d_ws;
    short* A2 = (short*)ws;                                            // 33,554,432 B
    char* p1c = ws + (size_t)BATCH * KP * 2;
    short* B2 = (short*)p1c;                                           //  4,194,304 B
    char* p2c = p1c + (size_t)OUT * KP * 2;
    __hip_bfloat16* P = (__hip_bfloat16*)p2c;                          // 16,777,216 B
    float* bias = (float*)(p2c + (size_t)SPLITK * BATCH * OUT * 2);    //      2,048 B

    prep<<<1280, 256, 0, stream>>>(x, w, coeff, A2, B2, bias);
    gemm_splitk<<<dim3(32, 4, SPLITK), 256, 0, stream>>>(A2, B2, P);
    reducek<<<BATCH * OUT / 8 / 256, 256, 0, stream>>>((const short*)P, bias, out);
}